// Round 16
// baseline (1824.475 us; speedup 1.0000x reference)
//
#include <hip/hip_runtime.h>
#include <math.h>

#define N_V    100000
#define N_E    200000
#define NNZ_C  1600000
#define NFEAT  128
#define NHID   64
#define NCLASS 40
#define NLAYER 8
#define ALPHA  0.1f

#define NWIN   8                 // one window per XCD (blockIdx&7 round-robin)
#define WE     (N_E / NWIN)      // 25000 edges per window
#define WV     (N_V / NWIN)      // 12500 vertices per window

#define MAXDE  48                // scratch stride, edge lists  (Poisson(8))
#define MAXDV  64                // scratch stride, vertex lists (Poisson(16))

typedef _Float16 f16;
typedef _Float16 f16x8 __attribute__((ext_vector_type(8)));   // 16 B
typedef _Float16 f16x2 __attribute__((ext_vector_type(2)));   // 4 B
typedef int      v4i   __attribute__((ext_vector_type(4)));   // 16 B

// Chunked feature layout: tensor[4][rows][16] f16. Chunk c holds features
// 16c..16c+15. Lane t (0..7) of a subgroup <-> chunk t>>1, half t&1.
// f16x8 index helpers (in f16x8 units): chunk stride = rows*2.

// ---------------------------------------------------------------------------
// FUSED one-pass count+place, BOTH sides (verified round 15).
__global__ __launch_bounds__(256) void k_place(const int* __restrict__ vertex,
                                               const int* __restrict__ edges,
                                               int* __restrict__ cntE,
                                               int* __restrict__ cntV,
                                               int* __restrict__ scrE,
                                               int* __restrict__ scrV) {
    const int win  = blockIdx.x & (NWIN - 1);
    const int blk  = blockIdx.x >> 3;
    const int nblk = gridDim.x >> 3;
    const int eLo = win * WE, eHi = eLo + WE;
    const int vLo = win * WV, vHi = vLo + WV;
    for (int z = blk * blockDim.x + threadIdx.x; z < NNZ_C; z += nblk * blockDim.x) {
        int v = __builtin_nontemporal_load(&vertex[z]);
        int e = __builtin_nontemporal_load(&edges[z]);
        if (e >= eLo && e < eHi) {
            int p = atomicAdd(&cntE[e], 1);
            if (p < MAXDE) scrE[e * MAXDE + p] = v;   // never triggers; safety
        }
        if (v >= vLo && v < vHi) {
            int p = atomicAdd(&cntV[v], 1);
            if (p < MAXDV) scrV[v * MAXDV + p] = e;
        }
    }
}

// h = relu(x @ W0 + b0) -> fp16 CHUNKED layout; h0 row layout. (round 13 core)
__global__ __launch_bounds__(256) void k_lin(const float* __restrict__ x,
                                             const float* __restrict__ W0,
                                             const float* __restrict__ b0,
                                             f16* __restrict__ h,
                                             f16* __restrict__ h0) {
    __shared__ float sW[NFEAT * NHID];   // 32 KB, row-major [k][f]
    __shared__ float sb[NHID];
    for (int i = threadIdx.x; i < NFEAT * NHID; i += blockDim.x) sW[i] = W0[i];
    if (threadIdx.x < NHID) sb[threadIdx.x] = b0[threadIdx.x];
    __syncthreads();
    const int lane = threadIdx.x & 63;
    const int t    = lane & 7;
    const int pair = blockIdx.x * 32 + (threadIdx.x >> 3);   // 32 subgroups/block
    if (pair >= N_V / 2) return;                              // N_V even
    const int r0 = 2 * pair, r1 = r0 + 1;
    const float4* __restrict__ x4 = (const float4*)x;         // 32 float4 per row
    float xr0[16], xr1[16];
    #pragma unroll
    for (int i = 0; i < 4; ++i) {
        float4 q0 = x4[(size_t)r0 * 32 + t * 4 + i];
        float4 q1 = x4[(size_t)r1 * 32 + t * 4 + i];
        xr0[4 * i + 0] = q0.x; xr0[4 * i + 1] = q0.y;
        xr0[4 * i + 2] = q0.z; xr0[4 * i + 3] = q0.w;
        xr1[4 * i + 0] = q1.x; xr1[4 * i + 1] = q1.y;
        xr1[4 * i + 2] = q1.z; xr1[4 * i + 3] = q1.w;
    }
    float a0[8], a1[8];
    #pragma unroll
    for (int j = 0; j < 8; ++j) { a0[j] = sb[8 * t + j]; a1[j] = a0[j]; }
    const int sgbase = lane & 56;
    #pragma unroll
    for (int k = 0; k < NFEAT; ++k) {
        float xk0 = __shfl(xr0[k & 15], sgbase | (k >> 4), 64);
        float xk1 = __shfl(xr1[k & 15], sgbase | (k >> 4), 64);
        const float4 wa = *(const float4*)&sW[k * NHID + 8 * t];
        const float4 wb = *(const float4*)&sW[k * NHID + 8 * t + 4];
        a0[0] = fmaf(xk0, wa.x, a0[0]);  a1[0] = fmaf(xk1, wa.x, a1[0]);
        a0[1] = fmaf(xk0, wa.y, a0[1]);  a1[1] = fmaf(xk1, wa.y, a1[1]);
        a0[2] = fmaf(xk0, wa.z, a0[2]);  a1[2] = fmaf(xk1, wa.z, a1[2]);
        a0[3] = fmaf(xk0, wa.w, a0[3]);  a1[3] = fmaf(xk1, wa.w, a1[3]);
        a0[4] = fmaf(xk0, wb.x, a0[4]);  a1[4] = fmaf(xk1, wb.x, a1[4]);
        a0[5] = fmaf(xk0, wb.y, a0[5]);  a1[5] = fmaf(xk1, wb.y, a1[5]);
        a0[6] = fmaf(xk0, wb.z, a0[6]);  a1[6] = fmaf(xk1, wb.z, a1[6]);
        a0[7] = fmaf(xk0, wb.w, a0[7]);  a1[7] = fmaf(xk1, wb.w, a1[7]);
    }
    f16x8 o0, o1;
    #pragma unroll
    for (int j = 0; j < 8; ++j) {
        o0[j] = (f16)fmaxf(a0[j], 0.0f);
        o1[j] = (f16)fmaxf(a1[j], 0.0f);
    }
    // h: chunked (lane t -> chunk t>>1, half t&1); h0: row layout
    const size_t hci = (size_t)(t >> 1) * (N_V * 2) + (t & 1);
    ((f16x8*)h )[hci + (size_t)r0 * 2] = o0;
    ((f16x8*)h )[hci + (size_t)r1 * 2] = o1;
    ((f16x8*)h0)[(size_t)r0 * 8 + t] = o0;
    ((f16x8*)h0)[(size_t)r1 * 8 + t] = o1;
}

// Xe = (sum h[v]) * degE/cnt — CHUNK-AFFINE (round 16). Chunk c (16 features,
// 3.2 MB of h) is gathered ONLY by XCDs {c, c+4} (blockIdx&7), so it stays
// L2-resident; all streams (cnt/degE/scr) use nt loads to avoid evicting it.
// 8-lane subgroup per edge per chunk; lane t reads/writes f16x2 (4 B).
// grid MUST be 8*3125 = 25000 blocks.
__global__ __launch_bounds__(256) void k_egather(const int* __restrict__ cntE,
                                                 const int* __restrict__ scrE,
                                                 const float* __restrict__ degE,
                                                 const f16* __restrict__ h,
                                                 f16* __restrict__ Xe) {
    const int xcd = blockIdx.x & 7;
    const int c   = xcd & 3;                       // chunk 0..3
    const int j   = ((blockIdx.x >> 3) << 1) | (xcd >> 2);  // stripe 0..6249
    const int sg  = threadIdx.x >> 3, t = threadIdx.x & 7;
    const int e   = j * 32 + sg;                   // exactly covers [0, 200000)
    const f16x2* __restrict__ hc = (const f16x2*)(h + (size_t)c * (N_V * 16));
    f16x2* __restrict__ xc = (f16x2*)(Xe + (size_t)c * (N_E * 16));
    const int cnt = min(__builtin_nontemporal_load(&cntE[e]), MAXDE);
    const float de = __builtin_nontemporal_load(&degE[e]);
    const float fac = (cnt > 0) ? de / (float)cnt : 0.0f;   // k_factor inlined
    const v4i* __restrict__ sr = (const v4i*)(scrE + (size_t)e * MAXDE);
    float a0 = 0.f, a1 = 0.f;
    for (int w = 0; w < cnt; w += 4) {
        v4i q = __builtin_nontemporal_load(&sr[w >> 2]);
        int i0 = q[0];
        int i1 = (w + 1 < cnt) ? q[1] : q[0];
        int i2 = (w + 2 < cnt) ? q[2] : q[0];
        int i3 = (w + 3 < cnt) ? q[3] : q[0];
        float m1 = (w + 1 < cnt) ? 1.f : 0.f;
        float m2 = (w + 2 < cnt) ? 1.f : 0.f;
        float m3 = (w + 3 < cnt) ? 1.f : 0.f;
        f16x2 v0 = hc[(size_t)i0 * 8 + t];         // normal loads: want L2 hits
        f16x2 v1 = hc[(size_t)i1 * 8 + t];
        f16x2 v2 = hc[(size_t)i2 * 8 + t];
        f16x2 v3 = hc[(size_t)i3 * 8 + t];
        a0 += (float)v0[0];
        a0 = fmaf(m1, (float)v1[0], a0);
        a0 = fmaf(m2, (float)v2[0], a0);
        a0 = fmaf(m3, (float)v3[0], a0);
        a1 += (float)v0[1];
        a1 = fmaf(m1, (float)v1[1], a1);
        a1 = fmaf(m2, (float)v2[1], a1);
        a1 = fmaf(m3, (float)v3[1], a1);
    }
    f16x2 o;
    o[0] = (f16)(a0 * fac);
    o[1] = (f16)(a1 * fac);
    xc[(size_t)e * 8 + t] = o;
}

// Fused vertex update (round 14 core). Xe now CHUNKED: lane t's 16 B live at
// chunk t>>1, row idx, half t&1. h output written CHUNKED; h0 read row-layout.
__global__ __launch_bounds__(256) void k_vertex_update(const int* __restrict__ cntV,
                                                       const int* __restrict__ scrV,
                                                       const f16* __restrict__ Xe,
                                                       const float* __restrict__ degV,
                                                       const f16* __restrict__ h0,
                                                       const float* __restrict__ Wi,
                                                       float beta,
                                                       f16* __restrict__ h) {
    __shared__ float sW[NHID * NHID];    // 16 KB, row-major [k][f]
    for (int i = threadIdx.x; i < NHID * NHID; i += blockDim.x) sW[i] = Wi[i];
    __syncthreads();
    const int lane = threadIdx.x & 63;
    const int sg = lane >> 3, t = lane & 7;
    const int n = (blockIdx.x * 4 + (threadIdx.x >> 6)) * 8 + sg; // 32 verts/block
    if (n >= N_V) return;
    const f16x8* __restrict__ xe8 = (const f16x8*)Xe;
    const size_t xcb = (size_t)(t >> 1) * (N_E * 2) + (t & 1);    // chunk base
    const int cnt = min(cntV[n], MAXDV);
    const int base = n * MAXDV;
    const float dv = degV[n];
    const f16x8 h0v = ((const f16x8*)h0)[(size_t)n * 8 + t];
    float acc[8] = {0.f, 0.f, 0.f, 0.f, 0.f, 0.f, 0.f, 0.f};
    for (int w = 0; w < cnt; w += 8) {
        int4 qa = *(const int4*)&scrV[base + w];
        int4 qb = *(const int4*)&scrV[base + w + 4];
        int   idx[8];
        float msk[8];
        idx[0] = qa.x;                       msk[0] = 1.f;
        idx[1] = (w + 1 < cnt) ? qa.y : qa.x; msk[1] = (w + 1 < cnt) ? 1.f : 0.f;
        idx[2] = (w + 2 < cnt) ? qa.z : qa.x; msk[2] = (w + 2 < cnt) ? 1.f : 0.f;
        idx[3] = (w + 3 < cnt) ? qa.w : qa.x; msk[3] = (w + 3 < cnt) ? 1.f : 0.f;
        idx[4] = (w + 4 < cnt) ? qb.x : qa.x; msk[4] = (w + 4 < cnt) ? 1.f : 0.f;
        idx[5] = (w + 5 < cnt) ? qb.y : qa.x; msk[5] = (w + 5 < cnt) ? 1.f : 0.f;
        idx[6] = (w + 6 < cnt) ? qb.z : qa.x; msk[6] = (w + 6 < cnt) ? 1.f : 0.f;
        idx[7] = (w + 7 < cnt) ? qb.w : qa.x; msk[7] = (w + 7 < cnt) ? 1.f : 0.f;
        f16x8 v[8];
        #pragma unroll
        for (int r = 0; r < 8; ++r) v[r] = xe8[xcb + (size_t)idx[r] * 2];
        #pragma unroll
        for (int j = 0; j < 8; ++j) {
            #pragma unroll
            for (int r = 0; r < 8; ++r)
                acc[j] = fmaf(msk[r], (float)v[r][j], acc[j]);
        }
    }
    float xv[8], ss = 0.f;
    #pragma unroll
    for (int j = 0; j < 8; ++j) { xv[j] = acc[j] * dv; ss = fmaf(xv[j], xv[j], ss); }
    #pragma unroll
    for (int off = 1; off <= 4; off <<= 1)
        ss += __shfl_xor(ss, off, 64);
    float rn  = sqrtf(ss);
    float inv = (rn > 0.0f) ? 1.0f / rn : 0.0f;
    float xi[8];
    #pragma unroll
    for (int j = 0; j < 8; ++j)
        xi[j] = (1.0f - ALPHA) * (xv[j] * inv) + ALPHA * (float)h0v[j];
    float y[8] = {0.f, 0.f, 0.f, 0.f, 0.f, 0.f, 0.f, 0.f};
    #pragma unroll
    for (int k = 0; k < NHID; ++k) {
        float xk = __shfl(xi[k & 7], 8 * sg + (k >> 3), 64);
        const float4 wa = *(const float4*)&sW[k * NHID + 8 * t];
        const float4 wb = *(const float4*)&sW[k * NHID + 8 * t + 4];
        y[0] = fmaf(xk, wa.x, y[0]);
        y[1] = fmaf(xk, wa.y, y[1]);
        y[2] = fmaf(xk, wa.z, y[2]);
        y[3] = fmaf(xk, wa.w, y[3]);
        y[4] = fmaf(xk, wb.x, y[4]);
        y[5] = fmaf(xk, wb.y, y[5]);
        y[6] = fmaf(xk, wb.z, y[6]);
        y[7] = fmaf(xk, wb.w, y[7]);
    }
    f16x8 o;
    #pragma unroll
    for (int j = 0; j < 8; ++j) {
        float v = fmaf(beta, y[j] - xi[j], xi[j]);
        o[j] = (f16)fmaxf(v, 0.0f);
    }
    ((f16x8*)h)[(size_t)(t >> 1) * (N_V * 2) + (size_t)n * 2 + (t & 1)] = o;
}

// out = h @ Wout + bout. (round 14 core; h now CHUNKED)
__global__ __launch_bounds__(256) void k_out(const f16* __restrict__ h,
                                             const float* __restrict__ Wout,
                                             const float* __restrict__ bout,
                                             float* __restrict__ out) {
    __shared__ float sW[NHID * NCLASS];  // 10 KB, row-major [k][c]
    __shared__ float sb[NCLASS];
    for (int i = threadIdx.x; i < NHID * NCLASS; i += blockDim.x) sW[i] = Wout[i];
    if (threadIdx.x < NCLASS) sb[threadIdx.x] = bout[threadIdx.x];
    __syncthreads();
    const int lane   = threadIdx.x & 63;
    const int t      = lane & 7;
    const int sgbase = lane & 56;
    const int pair   = blockIdx.x * 32 + (threadIdx.x >> 3);
    if (pair >= N_V / 2) return;
    const int r0 = 2 * pair, r1 = r0 + 1;
    const size_t hci = (size_t)(t >> 1) * (N_V * 2) + (t & 1);
    const f16x8 hv0 = ((const f16x8*)h)[hci + (size_t)r0 * 2];
    const f16x8 hv1 = ((const f16x8*)h)[hci + (size_t)r1 * 2];
    float h0r[8], h1r[8];
    #pragma unroll
    for (int j = 0; j < 8; ++j) { h0r[j] = (float)hv0[j]; h1r[j] = (float)hv1[j]; }
    float y0[5], y1[5];
    #pragma unroll
    for (int i = 0; i < 5; ++i) { y0[i] = sb[t + 8 * i]; y1[i] = y0[i]; }
    #pragma unroll
    for (int k = 0; k < NHID; ++k) {
        float hk0 = __shfl(h0r[k & 7], sgbase | (k >> 3), 64);
        float hk1 = __shfl(h1r[k & 7], sgbase | (k >> 3), 64);
        const float* wr = &sW[k * NCLASS];
        #pragma unroll
        for (int i = 0; i < 5; ++i) {
            float w = wr[t + 8 * i];
            y0[i] = fmaf(hk0, w, y0[i]);
            y1[i] = fmaf(hk1, w, y1[i]);
        }
    }
    #pragma unroll
    for (int i = 0; i < 5; ++i) {
        out[(size_t)r0 * NCLASS + t + 8 * i] = y0[i];
        out[(size_t)r1 * NCLASS + t + 8 * i] = y1[i];
    }
}

// ---------------------------------------------------------------------------
extern "C" void kernel_launch(void* const* d_in, const int* in_sizes, int n_in,
                              void* d_out, int out_size, void* d_ws, size_t ws_size,
                              hipStream_t stream) {
    const float* x      = (const float*)d_in[0];
    const int*   vertex = (const int*)  d_in[1];
    const int*   edges  = (const int*)  d_in[2];
    const float* degE   = (const float*)d_in[3];
    const float* degV   = (const float*)d_in[4];
    const float* W0     = (const float*)d_in[5];
    const float* b0     = (const float*)d_in[6];
    const float* Ws     = (const float*)d_in[7];
    const float* Wout   = (const float*)d_in[8];
    const float* bout   = (const float*)d_in[9];
    float* out = (float*)d_out;

    // workspace carve-up (~116 MB)
    char* p = (char*)d_ws;
    auto carve = [&](size_t bytes) { char* r = p; p += (bytes + 255) & ~(size_t)255; return r; };
    f16*   h0      = (f16*)  carve((size_t)N_V * NHID * sizeof(f16));    // 12.8 MB row
    f16*   hA      = (f16*)  carve((size_t)N_V * NHID * sizeof(f16));    // 12.8 MB chunked
    f16*   Xe      = (f16*)  carve((size_t)N_E * NHID * sizeof(f16));    // 25.6 MB chunked
    int*   cntE    = (int*)  carve((size_t)N_E * sizeof(int));           //  0.8 MB
    int*   cntV    = (int*)  carve((size_t)N_V * sizeof(int));           //  0.4 MB (contiguous after cntE)
    int*   scrE    = (int*)  carve((size_t)N_E * MAXDE * sizeof(int));   // 38.4 MB
    int*   scrV    = (int*)  carve((size_t)N_V * MAXDV * sizeof(int));   // 25.6 MB

    // ---- one-pass adjacency build (per call) ----
    // N_E*4 = 800000 B is 256-aligned, so cntV directly follows cntE:
    hipMemsetAsync(cntE, 0, (size_t)(N_E + N_V) * sizeof(int), stream);
    k_place<<<NWIN * 256, 256, 0, stream>>>(vertex, edges, cntE, cntV, scrE, scrV);

    // ---- network ----
    k_lin<<<(N_V / 2 + 31) / 32, 256, 0, stream>>>(x, W0, b0, hA, h0);

    for (int i = 0; i < NLAYER; ++i) {
        float beta = (float)log(0.5 / (double)(i + 1) + 1.0);
        k_egather<<<8 * 3125, 256, 0, stream>>>(cntE, scrE, degE, hA, Xe);
        k_vertex_update<<<(N_V + 31) / 32, 256, 0, stream>>>(cntV, scrV, Xe, degV, h0,
                                                             Ws + (size_t)i * NHID * NHID,
                                                             beta, hA);
    }
    k_out<<<(N_V / 2 + 31) / 32, 256, 0, stream>>>(hA, Wout, bout, out);
}

// Round 17
// 1821.156 us; speedup vs baseline: 1.0018x; 1.0018x over previous
//
#include <hip/hip_runtime.h>
#include <math.h>

#define N_V    100000
#define N_E    200000
#define NNZ_C  1600000
#define NFEAT  128
#define NHID   64
#define NCLASS 40
#define NLAYER 8
#define ALPHA  0.1f

#define NWIN   8                 // one window per XCD (blockIdx&7 round-robin)
#define WE     (N_E / NWIN)      // 25000 edges per window
#define WV     (N_V / NWIN)      // 12500 vertices per window

#define MAXDE  48                // scratch stride, edge lists  (Poisson(8))
#define MAXDV  64                // scratch stride, vertex lists (Poisson(16))

typedef _Float16 f16;
typedef _Float16 f16x8 __attribute__((ext_vector_type(8)));   // 16 B
typedef _Float16 f16x2 __attribute__((ext_vector_type(2)));   // 4 B
typedef int      v4i   __attribute__((ext_vector_type(4)));   // 16 B

// Chunked feature layout: tensor[4][rows][16] f16. Chunk c holds features
// 16c..16c+15. Lane t (0..7) of a subgroup <-> chunk t>>1, half t&1.
// f16x8 index helpers (in f16x8 units): chunk stride = rows*2.

// ---------------------------------------------------------------------------
// FUSED one-pass count+place, BOTH sides (verified round 15).
__global__ __launch_bounds__(256) void k_place(const int* __restrict__ vertex,
                                               const int* __restrict__ edges,
                                               int* __restrict__ cntE,
                                               int* __restrict__ cntV,
                                               int* __restrict__ scrE,
                                               int* __restrict__ scrV) {
    const int win  = blockIdx.x & (NWIN - 1);
    const int blk  = blockIdx.x >> 3;
    const int nblk = gridDim.x >> 3;
    const int eLo = win * WE, eHi = eLo + WE;
    const int vLo = win * WV, vHi = vLo + WV;
    for (int z = blk * blockDim.x + threadIdx.x; z < NNZ_C; z += nblk * blockDim.x) {
        int v = __builtin_nontemporal_load(&vertex[z]);
        int e = __builtin_nontemporal_load(&edges[z]);
        if (e >= eLo && e < eHi) {
            int p = atomicAdd(&cntE[e], 1);
            if (p < MAXDE) scrE[e * MAXDE + p] = v;   // never triggers; safety
        }
        if (v >= vLo && v < vHi) {
            int p = atomicAdd(&cntV[v], 1);
            if (p < MAXDV) scrV[v * MAXDV + p] = e;
        }
    }
}

// h = relu(x @ W0 + b0) -> fp16 CHUNKED layout; h0 row layout. (round 13 core)
__global__ __launch_bounds__(256) void k_lin(const float* __restrict__ x,
                                             const float* __restrict__ W0,
                                             const float* __restrict__ b0,
                                             f16* __restrict__ h,
                                             f16* __restrict__ h0) {
    __shared__ float sW[NFEAT * NHID];   // 32 KB, row-major [k][f]
    __shared__ float sb[NHID];
    for (int i = threadIdx.x; i < NFEAT * NHID; i += blockDim.x) sW[i] = W0[i];
    if (threadIdx.x < NHID) sb[threadIdx.x] = b0[threadIdx.x];
    __syncthreads();
    const int lane = threadIdx.x & 63;
    const int t    = lane & 7;
    const int pair = blockIdx.x * 32 + (threadIdx.x >> 3);   // 32 subgroups/block
    if (pair >= N_V / 2) return;                              // N_V even
    const int r0 = 2 * pair, r1 = r0 + 1;
    const float4* __restrict__ x4 = (const float4*)x;         // 32 float4 per row
    float xr0[16], xr1[16];
    #pragma unroll
    for (int i = 0; i < 4; ++i) {
        float4 q0 = x4[(size_t)r0 * 32 + t * 4 + i];
        float4 q1 = x4[(size_t)r1 * 32 + t * 4 + i];
        xr0[4 * i + 0] = q0.x; xr0[4 * i + 1] = q0.y;
        xr0[4 * i + 2] = q0.z; xr0[4 * i + 3] = q0.w;
        xr1[4 * i + 0] = q1.x; xr1[4 * i + 1] = q1.y;
        xr1[4 * i + 2] = q1.z; xr1[4 * i + 3] = q1.w;
    }
    float a0[8], a1[8];
    #pragma unroll
    for (int j = 0; j < 8; ++j) { a0[j] = sb[8 * t + j]; a1[j] = a0[j]; }
    const int sgbase = lane & 56;
    #pragma unroll
    for (int k = 0; k < NFEAT; ++k) {
        float xk0 = __shfl(xr0[k & 15], sgbase | (k >> 4), 64);
        float xk1 = __shfl(xr1[k & 15], sgbase | (k >> 4), 64);
        const float4 wa = *(const float4*)&sW[k * NHID + 8 * t];
        const float4 wb = *(const float4*)&sW[k * NHID + 8 * t + 4];
        a0[0] = fmaf(xk0, wa.x, a0[0]);  a1[0] = fmaf(xk1, wa.x, a1[0]);
        a0[1] = fmaf(xk0, wa.y, a0[1]);  a1[1] = fmaf(xk1, wa.y, a1[1]);
        a0[2] = fmaf(xk0, wa.z, a0[2]);  a1[2] = fmaf(xk1, wa.z, a1[2]);
        a0[3] = fmaf(xk0, wa.w, a0[3]);  a1[3] = fmaf(xk1, wa.w, a1[3]);
        a0[4] = fmaf(xk0, wb.x, a0[4]);  a1[4] = fmaf(xk1, wb.x, a1[4]);
        a0[5] = fmaf(xk0, wb.y, a0[5]);  a1[5] = fmaf(xk1, wb.y, a1[5]);
        a0[6] = fmaf(xk0, wb.z, a0[6]);  a1[6] = fmaf(xk1, wb.z, a1[6]);
        a0[7] = fmaf(xk0, wb.w, a0[7]);  a1[7] = fmaf(xk1, wb.w, a1[7]);
    }
    f16x8 o0, o1;
    #pragma unroll
    for (int j = 0; j < 8; ++j) {
        o0[j] = (f16)fmaxf(a0[j], 0.0f);
        o1[j] = (f16)fmaxf(a1[j], 0.0f);
    }
    // h: chunked (lane t -> chunk t>>1, half t&1); h0: row layout
    const size_t hci = (size_t)(t >> 1) * (N_V * 2) + (t & 1);
    ((f16x8*)h )[hci + (size_t)r0 * 2] = o0;
    ((f16x8*)h )[hci + (size_t)r1 * 2] = o1;
    ((f16x8*)h0)[(size_t)r0 * 8 + t] = o0;
    ((f16x8*)h0)[(size_t)r1 * 8 + t] = o1;
}

// Xe = (sum h[v]) * degE/cnt — CHUNK-AFFINE (round 16). Chunk c (16 features,
// 3.2 MB of h) is gathered ONLY by XCDs {c, c+4} (blockIdx&7), so it stays
// L2-resident; all streams (cnt/degE/scr) use nt loads to avoid evicting it.
// 8-lane subgroup per edge per chunk; lane t reads/writes f16x2 (4 B).
// grid MUST be 8*3125 = 25000 blocks.
__global__ __launch_bounds__(256) void k_egather(const int* __restrict__ cntE,
                                                 const int* __restrict__ scrE,
                                                 const float* __restrict__ degE,
                                                 const f16* __restrict__ h,
                                                 f16* __restrict__ Xe) {
    const int xcd = blockIdx.x & 7;
    const int c   = xcd & 3;                       // chunk 0..3
    const int j   = ((blockIdx.x >> 3) << 1) | (xcd >> 2);  // stripe 0..6249
    const int sg  = threadIdx.x >> 3, t = threadIdx.x & 7;
    const int e   = j * 32 + sg;                   // exactly covers [0, 200000)
    const f16x2* __restrict__ hc = (const f16x2*)(h + (size_t)c * (N_V * 16));
    f16x2* __restrict__ xc = (f16x2*)(Xe + (size_t)c * (N_E * 16));
    const int cnt = min(__builtin_nontemporal_load(&cntE[e]), MAXDE);
    const float de = __builtin_nontemporal_load(&degE[e]);
    const float fac = (cnt > 0) ? de / (float)cnt : 0.0f;   // k_factor inlined
    const v4i* __restrict__ sr = (const v4i*)(scrE + (size_t)e * MAXDE);
    float a0 = 0.f, a1 = 0.f;
    for (int w = 0; w < cnt; w += 4) {
        v4i q = __builtin_nontemporal_load(&sr[w >> 2]);
        int i0 = q[0];
        int i1 = (w + 1 < cnt) ? q[1] : q[0];
        int i2 = (w + 2 < cnt) ? q[2] : q[0];
        int i3 = (w + 3 < cnt) ? q[3] : q[0];
        float m1 = (w + 1 < cnt) ? 1.f : 0.f;
        float m2 = (w + 2 < cnt) ? 1.f : 0.f;
        float m3 = (w + 3 < cnt) ? 1.f : 0.f;
        f16x2 v0 = hc[(size_t)i0 * 8 + t];         // normal loads: want L2 hits
        f16x2 v1 = hc[(size_t)i1 * 8 + t];
        f16x2 v2 = hc[(size_t)i2 * 8 + t];
        f16x2 v3 = hc[(size_t)i3 * 8 + t];
        a0 += (float)v0[0];
        a0 = fmaf(m1, (float)v1[0], a0);
        a0 = fmaf(m2, (float)v2[0], a0);
        a0 = fmaf(m3, (float)v3[0], a0);
        a1 += (float)v0[1];
        a1 = fmaf(m1, (float)v1[1], a1);
        a1 = fmaf(m2, (float)v2[1], a1);
        a1 = fmaf(m3, (float)v3[1], a1);
    }
    f16x2 o;
    o[0] = (f16)(a0 * fac);
    o[1] = (f16)(a1 * fac);
    xc[(size_t)e * 8 + t] = o;
}

// Fused vertex update (round 14 core). Xe now CHUNKED: lane t's 16 B live at
// chunk t>>1, row idx, half t&1. h output written CHUNKED; h0 read row-layout.
__global__ __launch_bounds__(256) void k_vertex_update(const int* __restrict__ cntV,
                                                       const int* __restrict__ scrV,
                                                       const f16* __restrict__ Xe,
                                                       const float* __restrict__ degV,
                                                       const f16* __restrict__ h0,
                                                       const float* __restrict__ Wi,
                                                       float beta,
                                                       f16* __restrict__ h) {
    __shared__ float sW[NHID * NHID];    // 16 KB, row-major [k][f]
    for (int i = threadIdx.x; i < NHID * NHID; i += blockDim.x) sW[i] = Wi[i];
    __syncthreads();
    const int lane = threadIdx.x & 63;
    const int sg = lane >> 3, t = lane & 7;
    const int n = (blockIdx.x * 4 + (threadIdx.x >> 6)) * 8 + sg; // 32 verts/block
    if (n >= N_V) return;
    const f16x8* __restrict__ xe8 = (const f16x8*)Xe;
    const size_t xcb = (size_t)(t >> 1) * (N_E * 2) + (t & 1);    // chunk base
    const int cnt = min(cntV[n], MAXDV);
    const int base = n * MAXDV;
    const float dv = degV[n];
    const f16x8 h0v = ((const f16x8*)h0)[(size_t)n * 8 + t];
    float acc[8] = {0.f, 0.f, 0.f, 0.f, 0.f, 0.f, 0.f, 0.f};
    for (int w = 0; w < cnt; w += 8) {
        int4 qa = *(const int4*)&scrV[base + w];
        int4 qb = *(const int4*)&scrV[base + w + 4];
        int   idx[8];
        float msk[8];
        idx[0] = qa.x;                       msk[0] = 1.f;
        idx[1] = (w + 1 < cnt) ? qa.y : qa.x; msk[1] = (w + 1 < cnt) ? 1.f : 0.f;
        idx[2] = (w + 2 < cnt) ? qa.z : qa.x; msk[2] = (w + 2 < cnt) ? 1.f : 0.f;
        idx[3] = (w + 3 < cnt) ? qa.w : qa.x; msk[3] = (w + 3 < cnt) ? 1.f : 0.f;
        idx[4] = (w + 4 < cnt) ? qb.x : qa.x; msk[4] = (w + 4 < cnt) ? 1.f : 0.f;
        idx[5] = (w + 5 < cnt) ? qb.y : qa.x; msk[5] = (w + 5 < cnt) ? 1.f : 0.f;
        idx[6] = (w + 6 < cnt) ? qb.z : qa.x; msk[6] = (w + 6 < cnt) ? 1.f : 0.f;
        idx[7] = (w + 7 < cnt) ? qb.w : qa.x; msk[7] = (w + 7 < cnt) ? 1.f : 0.f;
        f16x8 v[8];
        #pragma unroll
        for (int r = 0; r < 8; ++r) v[r] = xe8[xcb + (size_t)idx[r] * 2];
        #pragma unroll
        for (int j = 0; j < 8; ++j) {
            #pragma unroll
            for (int r = 0; r < 8; ++r)
                acc[j] = fmaf(msk[r], (float)v[r][j], acc[j]);
        }
    }
    float xv[8], ss = 0.f;
    #pragma unroll
    for (int j = 0; j < 8; ++j) { xv[j] = acc[j] * dv; ss = fmaf(xv[j], xv[j], ss); }
    #pragma unroll
    for (int off = 1; off <= 4; off <<= 1)
        ss += __shfl_xor(ss, off, 64);
    float rn  = sqrtf(ss);
    float inv = (rn > 0.0f) ? 1.0f / rn : 0.0f;
    float xi[8];
    #pragma unroll
    for (int j = 0; j < 8; ++j)
        xi[j] = (1.0f - ALPHA) * (xv[j] * inv) + ALPHA * (float)h0v[j];
    float y[8] = {0.f, 0.f, 0.f, 0.f, 0.f, 0.f, 0.f, 0.f};
    #pragma unroll
    for (int k = 0; k < NHID; ++k) {
        float xk = __shfl(xi[k & 7], 8 * sg + (k >> 3), 64);
        const float4 wa = *(const float4*)&sW[k * NHID + 8 * t];
        const float4 wb = *(const float4*)&sW[k * NHID + 8 * t + 4];
        y[0] = fmaf(xk, wa.x, y[0]);
        y[1] = fmaf(xk, wa.y, y[1]);
        y[2] = fmaf(xk, wa.z, y[2]);
        y[3] = fmaf(xk, wa.w, y[3]);
        y[4] = fmaf(xk, wb.x, y[4]);
        y[5] = fmaf(xk, wb.y, y[5]);
        y[6] = fmaf(xk, wb.z, y[6]);
        y[7] = fmaf(xk, wb.w, y[7]);
    }
    f16x8 o;
    #pragma unroll
    for (int j = 0; j < 8; ++j) {
        float v = fmaf(beta, y[j] - xi[j], xi[j]);
        o[j] = (f16)fmaxf(v, 0.0f);
    }
    ((f16x8*)h)[(size_t)(t >> 1) * (N_V * 2) + (size_t)n * 2 + (t & 1)] = o;
}

// out = h @ Wout + bout. (round 14 core; h now CHUNKED)
__global__ __launch_bounds__(256) void k_out(const f16* __restrict__ h,
                                             const float* __restrict__ Wout,
                                             const float* __restrict__ bout,
                                             float* __restrict__ out) {
    __shared__ float sW[NHID * NCLASS];  // 10 KB, row-major [k][c]
    __shared__ float sb[NCLASS];
    for (int i = threadIdx.x; i < NHID * NCLASS; i += blockDim.x) sW[i] = Wout[i];
    if (threadIdx.x < NCLASS) sb[threadIdx.x] = bout[threadIdx.x];
    __syncthreads();
    const int lane   = threadIdx.x & 63;
    const int t      = lane & 7;
    const int sgbase = lane & 56;
    const int pair   = blockIdx.x * 32 + (threadIdx.x >> 3);
    if (pair >= N_V / 2) return;
    const int r0 = 2 * pair, r1 = r0 + 1;
    const size_t hci = (size_t)(t >> 1) * (N_V * 2) + (t & 1);
    const f16x8 hv0 = ((const f16x8*)h)[hci + (size_t)r0 * 2];
    const f16x8 hv1 = ((const f16x8*)h)[hci + (size_t)r1 * 2];
    float h0r[8], h1r[8];
    #pragma unroll
    for (int j = 0; j < 8; ++j) { h0r[j] = (float)hv0[j]; h1r[j] = (float)hv1[j]; }
    float y0[5], y1[5];
    #pragma unroll
    for (int i = 0; i < 5; ++i) { y0[i] = sb[t + 8 * i]; y1[i] = y0[i]; }
    #pragma unroll
    for (int k = 0; k < NHID; ++k) {
        float hk0 = __shfl(h0r[k & 7], sgbase | (k >> 3), 64);
        float hk1 = __shfl(h1r[k & 7], sgbase | (k >> 3), 64);
        const float* wr = &sW[k * NCLASS];
        #pragma unroll
        for (int i = 0; i < 5; ++i) {
            float w = wr[t + 8 * i];
            y0[i] = fmaf(hk0, w, y0[i]);
            y1[i] = fmaf(hk1, w, y1[i]);
        }
    }
    #pragma unroll
    for (int i = 0; i < 5; ++i) {
        out[(size_t)r0 * NCLASS + t + 8 * i] = y0[i];
        out[(size_t)r1 * NCLASS + t + 8 * i] = y1[i];
    }
}

// ---------------------------------------------------------------------------
extern "C" void kernel_launch(void* const* d_in, const int* in_sizes, int n_in,
                              void* d_out, int out_size, void* d_ws, size_t ws_size,
                              hipStream_t stream) {
    const float* x      = (const float*)d_in[0];
    const int*   vertex = (const int*)  d_in[1];
    const int*   edges  = (const int*)  d_in[2];
    const float* degE   = (const float*)d_in[3];
    const float* degV   = (const float*)d_in[4];
    const float* W0     = (const float*)d_in[5];
    const float* b0     = (const float*)d_in[6];
    const float* Ws     = (const float*)d_in[7];
    const float* Wout   = (const float*)d_in[8];
    const float* bout   = (const float*)d_in[9];
    float* out = (float*)d_out;

    // workspace carve-up (~116 MB)
    char* p = (char*)d_ws;
    auto carve = [&](size_t bytes) { char* r = p; p += (bytes + 255) & ~(size_t)255; return r; };
    f16*   h0      = (f16*)  carve((size_t)N_V * NHID * sizeof(f16));    // 12.8 MB row
    f16*   hA      = (f16*)  carve((size_t)N_V * NHID * sizeof(f16));    // 12.8 MB chunked
    f16*   Xe      = (f16*)  carve((size_t)N_E * NHID * sizeof(f16));    // 25.6 MB chunked
    int*   cntE    = (int*)  carve((size_t)N_E * sizeof(int));           //  0.8 MB
    int*   cntV    = (int*)  carve((size_t)N_V * sizeof(int));           //  0.4 MB (contiguous after cntE)
    int*   scrE    = (int*)  carve((size_t)N_E * MAXDE * sizeof(int));   // 38.4 MB
    int*   scrV    = (int*)  carve((size_t)N_V * MAXDV * sizeof(int));   // 25.6 MB

    // ---- one-pass adjacency build (per call) ----
    // N_E*4 = 800000 B is 256-aligned, so cntV directly follows cntE:
    hipMemsetAsync(cntE, 0, (size_t)(N_E + N_V) * sizeof(int), stream);
    k_place<<<NWIN * 256, 256, 0, stream>>>(vertex, edges, cntE, cntV, scrE, scrV);

    // ---- network ----
    k_lin<<<(N_V / 2 + 31) / 32, 256, 0, stream>>>(x, W0, b0, hA, h0);

    for (int i = 0; i < NLAYER; ++i) {
        float beta = (float)log(0.5 / (double)(i + 1) + 1.0);
        k_egather<<<8 * 3125, 256, 0, stream>>>(cntE, scrE, degE, hA, Xe);
        k_vertex_update<<<(N_V + 31) / 32, 256, 0, stream>>>(cntV, scrV, Xe, degV, h0,
                                                             Ws + (size_t)i * NHID * NHID,
                                                             beta, hA);
    }
    k_out<<<(N_V / 2 + 31) / 32, 256, 0, stream>>>(hA, Wout, bout, out);
}

// Round 18
// 935.305 us; speedup vs baseline: 1.9507x; 1.9471x over previous
//
#include <hip/hip_runtime.h>
#include <math.h>

#define N_V    100000
#define N_E    200000
#define NNZ_C  1600000
#define NFEAT  128
#define NHID   64
#define NCLASS 40
#define NLAYER 8
#define ALPHA  0.1f

#define NWIN   8                 // one window per XCD (blockIdx&7 round-robin)
#define WE     (N_E / NWIN)      // 25000 edges per window
#define WV     (N_V / NWIN)      // 12500 vertices per window

#define MAXDE  48                // scratch stride, edge lists  (Poisson(8))
#define MAXDV  64                // scratch stride, vertex lists (Poisson(16))

typedef _Float16 f16;
typedef _Float16 f16x8 __attribute__((ext_vector_type(8)));   // 16 B per lane

// ---------------------------------------------------------------------------
// FUSED one-pass count+place, BOTH sides (verified round 15).
// p = atomicAdd(cnt[..]) is simultaneously histogram and slot.
__global__ __launch_bounds__(256) void k_place(const int* __restrict__ vertex,
                                               const int* __restrict__ edges,
                                               int* __restrict__ cntE,
                                               int* __restrict__ cntV,
                                               int* __restrict__ scrE,
                                               int* __restrict__ scrV) {
    const int win  = blockIdx.x & (NWIN - 1);
    const int blk  = blockIdx.x >> 3;
    const int nblk = gridDim.x >> 3;
    const int eLo = win * WE, eHi = eLo + WE;
    const int vLo = win * WV, vHi = vLo + WV;
    for (int z = blk * blockDim.x + threadIdx.x; z < NNZ_C; z += nblk * blockDim.x) {
        int v = __builtin_nontemporal_load(&vertex[z]);
        int e = __builtin_nontemporal_load(&edges[z]);
        if (e >= eLo && e < eHi) {
            int p = atomicAdd(&cntE[e], 1);
            if (p < MAXDE) scrE[e * MAXDE + p] = v;   // never triggers; safety
        }
        if (v >= vLo && v < vHi) {
            int p = atomicAdd(&cntV[v], 1);
            if (p < MAXDV) scrV[v * MAXDV + p] = e;
        }
    }
}

// h = relu(x @ W0 + b0) -> fp16; also copy to h0. (verified round 13)
// 8-lane subgroup per ROW PAIR; W row read shared 8-way; 16 indep FMA chains.
__global__ __launch_bounds__(256) void k_lin(const float* __restrict__ x,
                                             const float* __restrict__ W0,
                                             const float* __restrict__ b0,
                                             f16* __restrict__ h,
                                             f16* __restrict__ h0) {
    __shared__ float sW[NFEAT * NHID];   // 32 KB, row-major [k][f]
    __shared__ float sb[NHID];
    for (int i = threadIdx.x; i < NFEAT * NHID; i += blockDim.x) sW[i] = W0[i];
    if (threadIdx.x < NHID) sb[threadIdx.x] = b0[threadIdx.x];
    __syncthreads();
    const int lane = threadIdx.x & 63;
    const int t    = lane & 7;
    const int pair = blockIdx.x * 32 + (threadIdx.x >> 3);   // 32 subgroups/block
    if (pair >= N_V / 2) return;                              // N_V even
    const int r0 = 2 * pair, r1 = r0 + 1;
    const float4* __restrict__ x4 = (const float4*)x;         // 32 float4 per row
    float xr0[16], xr1[16];
    #pragma unroll
    for (int i = 0; i < 4; ++i) {
        float4 q0 = x4[(size_t)r0 * 32 + t * 4 + i];
        float4 q1 = x4[(size_t)r1 * 32 + t * 4 + i];
        xr0[4 * i + 0] = q0.x; xr0[4 * i + 1] = q0.y;
        xr0[4 * i + 2] = q0.z; xr0[4 * i + 3] = q0.w;
        xr1[4 * i + 0] = q1.x; xr1[4 * i + 1] = q1.y;
        xr1[4 * i + 2] = q1.z; xr1[4 * i + 3] = q1.w;
    }
    float a0[8], a1[8];
    #pragma unroll
    for (int j = 0; j < 8; ++j) { a0[j] = sb[8 * t + j]; a1[j] = a0[j]; }
    const int sgbase = lane & 56;        // subgroup base lane within wave
    #pragma unroll
    for (int k = 0; k < NFEAT; ++k) {
        float xk0 = __shfl(xr0[k & 15], sgbase | (k >> 4), 64);
        float xk1 = __shfl(xr1[k & 15], sgbase | (k >> 4), 64);
        const float4 wa = *(const float4*)&sW[k * NHID + 8 * t];
        const float4 wb = *(const float4*)&sW[k * NHID + 8 * t + 4];
        a0[0] = fmaf(xk0, wa.x, a0[0]);  a1[0] = fmaf(xk1, wa.x, a1[0]);
        a0[1] = fmaf(xk0, wa.y, a0[1]);  a1[1] = fmaf(xk1, wa.y, a1[1]);
        a0[2] = fmaf(xk0, wa.z, a0[2]);  a1[2] = fmaf(xk1, wa.z, a1[2]);
        a0[3] = fmaf(xk0, wa.w, a0[3]);  a1[3] = fmaf(xk1, wa.w, a1[3]);
        a0[4] = fmaf(xk0, wb.x, a0[4]);  a1[4] = fmaf(xk1, wb.x, a1[4]);
        a0[5] = fmaf(xk0, wb.y, a0[5]);  a1[5] = fmaf(xk1, wb.y, a1[5]);
        a0[6] = fmaf(xk0, wb.z, a0[6]);  a1[6] = fmaf(xk1, wb.z, a1[6]);
        a0[7] = fmaf(xk0, wb.w, a0[7]);  a1[7] = fmaf(xk1, wb.w, a1[7]);
    }
    f16x8 o0, o1;
    #pragma unroll
    for (int j = 0; j < 8; ++j) {
        o0[j] = (f16)fmaxf(a0[j], 0.0f);
        o1[j] = (f16)fmaxf(a1[j], 0.0f);
    }
    ((f16x8*)h )[(size_t)r0 * 8 + t] = o0;
    ((f16x8*)h )[(size_t)r1 * 8 + t] = o1;
    ((f16x8*)h0)[(size_t)r0 * 8 + t] = o0;
    ((f16x8*)h0)[(size_t)r1 * 8 + t] = o1;
}

// Xe[e] = (sum over incident vertices of h[v]) * degE[e]/cnt[e]
// (verified round 15 structure; k_factor inlined — cntE is read anyway,
// degE nt-load replaces the factorE load: same traffic, one less kernel.)
// 8-lane-subgroup-per-edge, 4-deep masked batch; indices from the strided
// scratch row as ONE int4 load (16 B-aligned, always in-row).
__global__ __launch_bounds__(256) void k_edge_gather(const int* __restrict__ cntE,
                                                     const int* __restrict__ scrE,
                                                     const float* __restrict__ degE,
                                                     const f16* __restrict__ h,
                                                     f16* __restrict__ Xe) {
    const int lane = threadIdx.x & 63;
    const int sg = lane >> 3, t = lane & 7;
    const int e = (blockIdx.x * 4 + (threadIdx.x >> 6)) * 8 + sg;  // 32 edges/block
    if (e >= N_E) return;
    const f16x8* __restrict__ hv = (const f16x8*)h;
    const int cnt = min(cntE[e], MAXDE);
    const int base = e * MAXDE;
    const float de = __builtin_nontemporal_load(&degE[e]);
    const float fac = (cnt > 0) ? de / (float)cnt : 0.0f;
    float acc[8] = {0.f, 0.f, 0.f, 0.f, 0.f, 0.f, 0.f, 0.f};
    for (int w = 0; w < cnt; w += 4) {
        int4 q = *(const int4*)&scrE[base + w];     // slots w..w+3 (w<cnt => q.x valid)
        int i0 = q.x;
        int i1 = (w + 1 < cnt) ? q.y : q.x;         // clamp garbage slots to a valid idx
        int i2 = (w + 2 < cnt) ? q.z : q.x;
        int i3 = (w + 3 < cnt) ? q.w : q.x;
        float m1 = (w + 1 < cnt) ? 1.f : 0.f;
        float m2 = (w + 2 < cnt) ? 1.f : 0.f;
        float m3 = (w + 3 < cnt) ? 1.f : 0.f;
        f16x8 v0 = hv[(size_t)i0 * 8 + t];
        f16x8 v1 = hv[(size_t)i1 * 8 + t];
        f16x8 v2 = hv[(size_t)i2 * 8 + t];
        f16x8 v3 = hv[(size_t)i3 * 8 + t];
        #pragma unroll
        for (int j = 0; j < 8; ++j) {
            acc[j] += (float)v0[j];
            acc[j] = fmaf(m1, (float)v1[j], acc[j]);
            acc[j] = fmaf(m2, (float)v2[j], acc[j]);
            acc[j] = fmaf(m3, (float)v3[j], acc[j]);
        }
    }
    f16x8 o;
    #pragma unroll
    for (int j = 0; j < 8; ++j) o[j] = (f16)(acc[j] * fac);
    ((f16x8*)Xe)[(size_t)e * 8 + t] = o;
}

// Fused: Xv = (sum over incident edges of Xe[e]) * degV  ->  L2 rownorm ->
// GCNII mix -> 64x64 GEMM -> relu -> fp16. (verified round 14/15)
// 8-lane-subgroup-per-vertex, 8-deep masked batch; indices via two int4 loads.
__global__ __launch_bounds__(256) void k_vertex_update(const int* __restrict__ cntV,
                                                       const int* __restrict__ scrV,
                                                       const f16* __restrict__ Xe,
                                                       const float* __restrict__ degV,
                                                       const f16* __restrict__ h0,
                                                       const float* __restrict__ Wi,
                                                       float beta,
                                                       f16* __restrict__ h) {
    __shared__ float sW[NHID * NHID];    // 16 KB, row-major [k][f]
    for (int i = threadIdx.x; i < NHID * NHID; i += blockDim.x) sW[i] = Wi[i];
    __syncthreads();
    const int lane = threadIdx.x & 63;
    const int sg = lane >> 3, t = lane & 7;
    const int n = (blockIdx.x * 4 + (threadIdx.x >> 6)) * 8 + sg; // 32 verts/block
    if (n >= N_V) return;
    const f16x8* __restrict__ xe = (const f16x8*)Xe;
    const int cnt = min(cntV[n], MAXDV);
    const int base = n * MAXDV;
    const float dv = degV[n];
    const f16x8 h0v = ((const f16x8*)h0)[(size_t)n * 8 + t];
    float acc[8] = {0.f, 0.f, 0.f, 0.f, 0.f, 0.f, 0.f, 0.f};
    for (int w = 0; w < cnt; w += 8) {
        int4 qa = *(const int4*)&scrV[base + w];        // w multiple of 8 -> aligned
        int4 qb = *(const int4*)&scrV[base + w + 4];    // always in-row (w+7 <= 63)
        int   idx[8];
        float msk[8];
        idx[0] = qa.x;                       msk[0] = 1.f;   // w<cnt guaranteed
        idx[1] = (w + 1 < cnt) ? qa.y : qa.x; msk[1] = (w + 1 < cnt) ? 1.f : 0.f;
        idx[2] = (w + 2 < cnt) ? qa.z : qa.x; msk[2] = (w + 2 < cnt) ? 1.f : 0.f;
        idx[3] = (w + 3 < cnt) ? qa.w : qa.x; msk[3] = (w + 3 < cnt) ? 1.f : 0.f;
        idx[4] = (w + 4 < cnt) ? qb.x : qa.x; msk[4] = (w + 4 < cnt) ? 1.f : 0.f;
        idx[5] = (w + 5 < cnt) ? qb.y : qa.x; msk[5] = (w + 5 < cnt) ? 1.f : 0.f;
        idx[6] = (w + 6 < cnt) ? qb.z : qa.x; msk[6] = (w + 6 < cnt) ? 1.f : 0.f;
        idx[7] = (w + 7 < cnt) ? qb.w : qa.x; msk[7] = (w + 7 < cnt) ? 1.f : 0.f;
        f16x8 v[8];
        #pragma unroll
        for (int r = 0; r < 8; ++r) v[r] = xe[(size_t)idx[r] * 8 + t];
        #pragma unroll
        for (int j = 0; j < 8; ++j) {
            #pragma unroll
            for (int r = 0; r < 8; ++r)
                acc[j] = fmaf(msk[r], (float)v[r][j], acc[j]);
        }
    }
    // scale by degV FIRST, then norm of the scaled row (matches reference)
    float xv[8], ss = 0.f;
    #pragma unroll
    for (int j = 0; j < 8; ++j) { xv[j] = acc[j] * dv; ss = fmaf(xv[j], xv[j], ss); }
    #pragma unroll
    for (int off = 1; off <= 4; off <<= 1)   // reduce within the 8-lane subgroup
        ss += __shfl_xor(ss, off, 64);
    float rn  = sqrtf(ss);
    float inv = (rn > 0.0f) ? 1.0f / rn : 0.0f;
    float xi[8];
    #pragma unroll
    for (int j = 0; j < 8; ++j)
        xi[j] = (1.0f - ALPHA) * (xv[j] * inv) + ALPHA * (float)h0v[j];
    // y_f = sum_k xi_k * W[k][f], f = 8t+j; xi_k owned by lane 8*sg+(k>>3),
    // component k&7. Uniform k-loop; LDS float4 reads are 2-way alias (free).
    float y[8] = {0.f, 0.f, 0.f, 0.f, 0.f, 0.f, 0.f, 0.f};
    #pragma unroll
    for (int k = 0; k < NHID; ++k) {
        float xk = __shfl(xi[k & 7], 8 * sg + (k >> 3), 64);
        const float4 wa = *(const float4*)&sW[k * NHID + 8 * t];
        const float4 wb = *(const float4*)&sW[k * NHID + 8 * t + 4];
        y[0] = fmaf(xk, wa.x, y[0]);
        y[1] = fmaf(xk, wa.y, y[1]);
        y[2] = fmaf(xk, wa.z, y[2]);
        y[3] = fmaf(xk, wa.w, y[3]);
        y[4] = fmaf(xk, wb.x, y[4]);
        y[5] = fmaf(xk, wb.y, y[5]);
        y[6] = fmaf(xk, wb.z, y[6]);
        y[7] = fmaf(xk, wb.w, y[7]);
    }
    f16x8 o;
    #pragma unroll
    for (int j = 0; j < 8; ++j) {
        float v = fmaf(beta, y[j] - xi[j], xi[j]);   // (1-b)*xi + b*y
        o[j] = (f16)fmaxf(v, 0.0f);
    }
    ((f16x8*)h)[(size_t)n * 8 + t] = o;
}

// out = h @ Wout + bout. (verified round 14)
// 8-lane subgroup per ROW PAIR; lane t owns classes c = t+8i (i<5).
__global__ __launch_bounds__(256) void k_out(const f16* __restrict__ h,
                                             const float* __restrict__ Wout,
                                             const float* __restrict__ bout,
                                             float* __restrict__ out) {
    __shared__ float sW[NHID * NCLASS];  // 10 KB, row-major [k][c]
    __shared__ float sb[NCLASS];
    for (int i = threadIdx.x; i < NHID * NCLASS; i += blockDim.x) sW[i] = Wout[i];
    if (threadIdx.x < NCLASS) sb[threadIdx.x] = bout[threadIdx.x];
    __syncthreads();
    const int lane   = threadIdx.x & 63;
    const int t      = lane & 7;
    const int sgbase = lane & 56;
    const int pair   = blockIdx.x * 32 + (threadIdx.x >> 3);  // 32 subgroups/block
    if (pair >= N_V / 2) return;                              // N_V even
    const int r0 = 2 * pair, r1 = r0 + 1;
    const f16x8 hv0 = ((const f16x8*)h)[(size_t)r0 * 8 + t];
    const f16x8 hv1 = ((const f16x8*)h)[(size_t)r1 * 8 + t];
    float h0r[8], h1r[8];
    #pragma unroll
    for (int j = 0; j < 8; ++j) { h0r[j] = (float)hv0[j]; h1r[j] = (float)hv1[j]; }
    float y0[5], y1[5];
    #pragma unroll
    for (int i = 0; i < 5; ++i) { y0[i] = sb[t + 8 * i]; y1[i] = y0[i]; }
    #pragma unroll
    for (int k = 0; k < NHID; ++k) {
        float hk0 = __shfl(h0r[k & 7], sgbase | (k >> 3), 64);
        float hk1 = __shfl(h1r[k & 7], sgbase | (k >> 3), 64);
        const float* wr = &sW[k * NCLASS];
        #pragma unroll
        for (int i = 0; i < 5; ++i) {
            float w = wr[t + 8 * i];
            y0[i] = fmaf(hk0, w, y0[i]);
            y1[i] = fmaf(hk1, w, y1[i]);
        }
    }
    #pragma unroll
    for (int i = 0; i < 5; ++i) {
        out[(size_t)r0 * NCLASS + t + 8 * i] = y0[i];
        out[(size_t)r1 * NCLASS + t + 8 * i] = y1[i];
    }
}

// ---------------------------------------------------------------------------
extern "C" void kernel_launch(void* const* d_in, const int* in_sizes, int n_in,
                              void* d_out, int out_size, void* d_ws, size_t ws_size,
                              hipStream_t stream) {
    const float* x      = (const float*)d_in[0];
    const int*   vertex = (const int*)  d_in[1];
    const int*   edges  = (const int*)  d_in[2];
    const float* degE   = (const float*)d_in[3];
    const float* degV   = (const float*)d_in[4];
    const float* W0     = (const float*)d_in[5];
    const float* b0     = (const float*)d_in[6];
    const float* Ws     = (const float*)d_in[7];
    const float* Wout   = (const float*)d_in[8];
    const float* bout   = (const float*)d_in[9];
    float* out = (float*)d_out;

    // workspace carve-up (~116 MB)
    char* p = (char*)d_ws;
    auto carve = [&](size_t bytes) { char* r = p; p += (bytes + 255) & ~(size_t)255; return r; };
    f16*   h0      = (f16*)  carve((size_t)N_V * NHID * sizeof(f16));    // 12.8 MB
    f16*   hA      = (f16*)  carve((size_t)N_V * NHID * sizeof(f16));    // 12.8 MB
    f16*   Xe      = (f16*)  carve((size_t)N_E * NHID * sizeof(f16));    // 25.6 MB
    int*   cntE    = (int*)  carve((size_t)N_E * sizeof(int));           //  0.8 MB
    int*   cntV    = (int*)  carve((size_t)N_V * sizeof(int));           //  0.4 MB (contiguous after cntE)
    int*   scrE    = (int*)  carve((size_t)N_E * MAXDE * sizeof(int));   // 38.4 MB
    int*   scrV    = (int*)  carve((size_t)N_V * MAXDV * sizeof(int));   // 25.6 MB

    // ---- one-pass adjacency build (per call) ----
    // N_E*4 = 800000 B is 256-aligned, so cntV directly follows cntE:
    hipMemsetAsync(cntE, 0, (size_t)(N_E + N_V) * sizeof(int), stream);
    k_place<<<NWIN * 256, 256, 0, stream>>>(vertex, edges, cntE, cntV, scrE, scrV);

    // ---- network ----
    k_lin<<<(N_V / 2 + 31) / 32, 256, 0, stream>>>(x, W0, b0, hA, h0);

    for (int i = 0; i < NLAYER; ++i) {
        float beta = (float)log(0.5 / (double)(i + 1) + 1.0);
        k_edge_gather  <<<(N_E + 31) / 32, 256, 0, stream>>>(cntE, scrE, degE, hA, Xe);
        k_vertex_update<<<(N_V + 31) / 32, 256, 0, stream>>>(cntV, scrV, Xe, degV, h0,
                                                             Ws + (size_t)i * NHID * NHID,
                                                             beta, hA);
    }
    k_out<<<(N_V / 2 + 31) / 32, 256, 0, stream>>>(hA, Wout, bout, out);
}